// Round 4
// baseline (790.831 us; speedup 1.0000x reference)
//
#include <hip/hip_runtime.h>

#define NPTS 120000
#define NB   60000
#define TAPS 27

typedef short  short8 __attribute__((ext_vector_type(8)));
typedef float  f32x4  __attribute__((ext_vector_type(4)));

__device__ __forceinline__ unsigned short f2bf(float f) {
  unsigned v; __builtin_memcpy(&v, &f, 4);
  v = v + 0x7FFFu + ((v >> 16) & 1u);   // RNE (finite values only)
  return (unsigned short)(v >> 16);
}

// ---- invert kernel map: nbr[k*N + out_row] = in_row (else -1 from memset) ----
__global__ __launch_bounds__(256) void k_build_nbr(const int* __restrict__ oi,
                                                   const int* __restrict__ ii,
                                                   int* __restrict__ nbr) {
  int g = blockIdx.x * 256 + threadIdx.x;
  if (g >= TAPS * NPTS) return;
  int o = oi[g];
  if (o < NPTS) nbr[(g / NPTS) * NPTS + o] = ii[g];
}

// ---- repack w_blocks (f32, 4 layers x 27 x 64 x 64) into bf16 MFMA B-fragment order ----
// dst[((L*27+k)*8 + t*2+h)*512 + lane*8 + e] = bf16(w[L][k][h*32+(lane>>4)*8+e][t*16+(lane&15)])
__global__ __launch_bounds__(256) void k_repack(const float* __restrict__ w,
                                                unsigned short* __restrict__ wp) {
  int g = blockIdx.x * 256 + threadIdx.x;          // 108*4096 total
  int e = g & 7, l = (g >> 3) & 63, f = (g >> 9) & 7, rest = g >> 12; // rest = L*27+k
  int t = f >> 1, h = f & 1;
  int kk = h * 32 + (l >> 4) * 8 + e;
  int cc = t * 16 + (l & 15);
  wp[g] = f2bf(w[(rest * 64 + kk) * 64 + cc]);
}

// ---- instance-norm stats pass 1: per-block partial sum/sumsq per channel ----
__global__ __launch_bounds__(256) void k_stats1(const float* __restrict__ F,
                                                float* __restrict__ P) {
  int lane = threadIdx.x & 63, wave = threadIdx.x >> 6;
  int batch = blockIdx.x >> 7, bb = blockIdx.x & 127;   // 128 blocks per batch
  const float* Fb = F + (size_t)batch * NB * 64;
  float s = 0.f, ss = 0.f;
  for (int r = bb * 4 + wave; r < NB; r += 512) {
    float v = Fb[r * 64 + lane];
    s += v; ss += v * v;
  }
  __shared__ float ls[4][64], lss[4][64];
  ls[wave][lane] = s; lss[wave][lane] = ss;
  __syncthreads();
  if (threadIdx.x < 64) {
    float S  = ls[0][lane] + ls[1][lane] + ls[2][lane] + ls[3][lane];
    float SS = lss[0][lane] + lss[1][lane] + lss[2][lane] + lss[3][lane];
    P[blockIdx.x * 128 + lane]      = S;
    P[blockIdx.x * 128 + 64 + lane] = SS;
  }
}

// ---- stats pass 2: reduce 128 partials/batch -> mean, rstd ----
__global__ void k_stats2(const float* __restrict__ P, float* __restrict__ MRS) {
  int t = threadIdx.x;
  if (t >= 128) return;
  int b = t >> 6, c = t & 63;
  float S = 0.f, SS = 0.f;
  for (int blk = 0; blk < 128; ++blk) {
    S  += P[(b * 128 + blk) * 128 + c];
    SS += P[(b * 128 + blk) * 128 + 64 + c];
  }
  float mean = S * (1.f / NB);
  float var  = SS * (1.f / NB) - mean * mean;
  MRS[b * 128 + c]      = mean;
  MRS[b * 128 + 64 + c] = rsqrtf(var + 1e-5f);
}

// ---- O = relu(norm(F)) elementwise, float4 per thread (in-place safe) ----
__global__ __launch_bounds__(256) void k_apply(const float* __restrict__ F,
                                               const float* __restrict__ MRS,
                                               float* __restrict__ O) {
  int i = blockIdx.x * 256 + threadIdx.x;          // < 1,920,000
  int r = i >> 4, cb = (i & 15) * 4;
  int b = (r >= NB) ? 1 : 0;
  f32x4 v = *((const f32x4*)F + i);
  f32x4 o;
#pragma unroll
  for (int e = 0; e < 4; ++e) {
    float f = (v[e] - MRS[b * 128 + cb + e]) * MRS[b * 128 + 64 + cb + e];
    o[e] = fmaxf(f, 0.f);
  }
  *((f32x4*)O + i) = o;
}

// ---- X = relu(norm(H2) + X) ----
__global__ __launch_bounds__(256) void k_apply_res(const float* __restrict__ H2,
                                                   const float* __restrict__ MRS,
                                                   float* __restrict__ X) {
  int i = blockIdx.x * 256 + threadIdx.x;
  int r = i >> 4, cb = (i & 15) * 4;
  int b = (r >= NB) ? 1 : 0;
  f32x4 v = *((const f32x4*)H2 + i);
  f32x4 xv = *((const f32x4*)X + i);
  f32x4 o;
#pragma unroll
  for (int e = 0; e < 4; ++e) {
    float f = (v[e] - MRS[b * 128 + cb + e]) * MRS[b * 128 + 64 + cb + e];
    o[e] = fmaxf(f + xv[e], 0.f);
  }
  *((f32x4*)X + i) = o;
}

// ---- gather-MFMA sparse conv, 64->64, f32 in/out, bf16 fragments ----
__global__ __launch_bounds__(256) void k_conv64(const float* __restrict__ X,
                                                const unsigned short* __restrict__ WP,
                                                const int* __restrict__ nbr,
                                                float* __restrict__ Y) {
  const int lane = threadIdx.x & 63, wave = threadIdx.x >> 6;
  const int j0 = blockIdx.x * 64 + wave * 16;
  const int lrow = lane & 15, lk = lane >> 4;
  f32x4 acc0 = {0,0,0,0}, acc1 = {0,0,0,0}, acc2 = {0,0,0,0}, acc3 = {0,0,0,0};
  for (int k = 0; k < TAPS; ++k) {
    int idx = nbr[k * NPTS + j0 + lrow];
    bool valid = idx >= 0;
    if (__ballot(valid) == 0ull) continue;       // wave-uniform skip
    short8 a0 = {0,0,0,0,0,0,0,0}, a1 = {0,0,0,0,0,0,0,0};
    if (valid) {
      const float* rp = X + (size_t)idx * 64 + lk * 8;
      f32x4 x0 = *(const f32x4*)rp;
      f32x4 x1 = *(const f32x4*)(rp + 4);
      f32x4 x2 = *(const f32x4*)(rp + 32);
      f32x4 x3 = *(const f32x4*)(rp + 36);
#pragma unroll
      for (int e = 0; e < 4; ++e) {
        a0[e]     = (short)f2bf(x0[e]);
        a0[e + 4] = (short)f2bf(x1[e]);
        a1[e]     = (short)f2bf(x2[e]);
        a1[e + 4] = (short)f2bf(x3[e]);
      }
    }
    const unsigned short* wp = WP + k * 4096 + lane * 8;
    short8 b;
    b = *(const short8*)(wp +    0); acc0 = __builtin_amdgcn_mfma_f32_16x16x32_bf16(a0, b, acc0, 0, 0, 0);
    b = *(const short8*)(wp +  512); acc0 = __builtin_amdgcn_mfma_f32_16x16x32_bf16(a1, b, acc0, 0, 0, 0);
    b = *(const short8*)(wp + 1024); acc1 = __builtin_amdgcn_mfma_f32_16x16x32_bf16(a0, b, acc1, 0, 0, 0);
    b = *(const short8*)(wp + 1536); acc1 = __builtin_amdgcn_mfma_f32_16x16x32_bf16(a1, b, acc1, 0, 0, 0);
    b = *(const short8*)(wp + 2048); acc2 = __builtin_amdgcn_mfma_f32_16x16x32_bf16(a0, b, acc2, 0, 0, 0);
    b = *(const short8*)(wp + 2560); acc2 = __builtin_amdgcn_mfma_f32_16x16x32_bf16(a1, b, acc2, 0, 0, 0);
    b = *(const short8*)(wp + 3072); acc3 = __builtin_amdgcn_mfma_f32_16x16x32_bf16(a0, b, acc3, 0, 0, 0);
    b = *(const short8*)(wp + 3584); acc3 = __builtin_amdgcn_mfma_f32_16x16x32_bf16(a1, b, acc3, 0, 0, 0);
  }
  // C/D layout: col = lane&15, row = (lane>>4)*4 + reg   [m89-verified]
  float* yp = Y + (size_t)(j0 + lk * 4) * 64 + (lane & 15);
#pragma unroll
  for (int r = 0; r < 4; ++r) {
    yp[r * 64 +  0] = acc0[r];
    yp[r * 64 + 16] = acc1[r];
    yp[r * 64 + 32] = acc2[r];
    yp[r * 64 + 48] = acc3[r];
  }
}

// ---- final conv 64->1 + bias (all f32 math), one wave per output row, f32 out ----
__global__ __launch_bounds__(256) void k_convfin(const float* __restrict__ X,
                                                 const float* __restrict__ WF,
                                                 const float* __restrict__ BF,
                                                 const int* __restrict__ nbr,
                                                 float* __restrict__ out) {
  int lane = threadIdx.x & 63, wave = threadIdx.x >> 6;
  int j = blockIdx.x * 4 + wave;
  float acc = 0.f;
  for (int k = 0; k < TAPS; ++k) {
    int idx = nbr[k * NPTS + j];
    if (idx >= 0)
      acc += X[(size_t)idx * 64 + lane] * WF[k * 64 + lane];
  }
#pragma unroll
  for (int off = 32; off >= 1; off >>= 1) acc += __shfl_xor(acc, off, 64);
  if (lane == 0) out[j] = acc + BF[0];
}

extern "C" void kernel_launch(void* const* d_in, const int* in_sizes, int n_in,
                              void* d_out, int out_size, void* d_ws, size_t ws_size,
                              hipStream_t stream) {
  (void)in_sizes; (void)n_in; (void)out_size; (void)ws_size;
  const float* feats = (const float*)d_in[0];
  const float* wblk  = (const float*)d_in[1];
  const float* wfin  = (const float*)d_in[2];
  const float* bfin  = (const float*)d_in[3];
  const int* in_idx  = (const int*)d_in[4];
  const int* out_idx = (const int*)d_in[5];

  char* p = (char*)d_ws;
  size_t off = 0;
  auto carve = [&](size_t bytes) {
    void* r = p + off; off += (bytes + 255) & ~(size_t)255; return r;
  };
  int*            nbr = (int*)carve((size_t)TAPS * NPTS * 4);        // 12.96 MB
  float*          Xb  = (float*)carve((size_t)NPTS * 64 * 4);        // 30.72 MB
  float*          Hb  = (float*)carve((size_t)NPTS * 64 * 4);
  float*          H2b = (float*)carve((size_t)NPTS * 64 * 4);
  unsigned short* WP  = (unsigned short*)carve(108u * 4096u * 2);    // 0.88 MB
  float*          P   = (float*)carve(256 * 128 * 4);
  float*          MRS = (float*)carve(256 * 4);

  hipMemsetAsync(nbr, 0xFF, (size_t)TAPS * NPTS * 4, stream);
  k_build_nbr<<<(TAPS * NPTS + 255) / 256, 256, 0, stream>>>(out_idx, in_idx, nbr);
  k_repack<<<1728, 256, 0, stream>>>(wblk, WP);

  // x = relu(IN(feats))
  k_stats1<<<256, 256, 0, stream>>>(feats, P);
  k_stats2<<<1, 128, 0, stream>>>(P, MRS);
  k_apply<<<7500, 256, 0, stream>>>(feats, MRS, Xb);

  // block 0
  k_conv64<<<1875, 256, 0, stream>>>(Xb, WP + 0 * 110592, nbr, Hb);
  k_stats1<<<256, 256, 0, stream>>>(Hb, P);
  k_stats2<<<1, 128, 0, stream>>>(P, MRS);
  k_apply<<<7500, 256, 0, stream>>>(Hb, MRS, Hb);
  k_conv64<<<1875, 256, 0, stream>>>(Hb, WP + 1 * 110592, nbr, H2b);
  k_stats1<<<256, 256, 0, stream>>>(H2b, P);
  k_stats2<<<1, 128, 0, stream>>>(P, MRS);
  k_apply_res<<<7500, 256, 0, stream>>>(H2b, MRS, Xb);

  // block 1
  k_conv64<<<1875, 256, 0, stream>>>(Xb, WP + 2 * 110592, nbr, Hb);
  k_stats1<<<256, 256, 0, stream>>>(Hb, P);
  k_stats2<<<1, 128, 0, stream>>>(P, MRS);
  k_apply<<<7500, 256, 0, stream>>>(Hb, MRS, Hb);
  k_conv64<<<1875, 256, 0, stream>>>(Hb, WP + 3 * 110592, nbr, H2b);
  k_stats1<<<256, 256, 0, stream>>>(H2b, P);
  k_stats2<<<1, 128, 0, stream>>>(P, MRS);
  k_apply_res<<<7500, 256, 0, stream>>>(H2b, MRS, Xb);

  // final 64->1 conv + bias
  k_convfin<<<NPTS / 4, 256, 0, stream>>>(Xb, wfin, bfin, nbr, (float*)d_out);
}

// Round 5
// 510.513 us; speedup vs baseline: 1.5491x; 1.5491x over previous
//
#include <hip/hip_runtime.h>

#define NPTS 120000
#define NROW 120064   // padded row count (multiple of 256)
#define NB   60000
#define TAPS 27

typedef short  short8 __attribute__((ext_vector_type(8)));
typedef float  f32x4  __attribute__((ext_vector_type(4)));

__device__ __forceinline__ float bf2f(unsigned short u) {
  unsigned v = ((unsigned)u) << 16;
  float f; __builtin_memcpy(&f, &v, 4); return f;
}
__device__ __forceinline__ unsigned short f2bf(float f) {
  unsigned v; __builtin_memcpy(&v, &f, 4);
  v = v + 0x7FFFu + ((v >> 16) & 1u);   // RNE (finite values only)
  return (unsigned short)(v >> 16);
}

// ---- invert kernel map: nbr[k*NROW + out_row] = in_row (else -1 from memset) ----
__global__ __launch_bounds__(256) void k_build_nbr(const int* __restrict__ oi,
                                                   const int* __restrict__ ii,
                                                   int* __restrict__ nbr) {
  int g = blockIdx.x * 256 + threadIdx.x;
  if (g >= TAPS * NPTS) return;
  int o = oi[g];
  if (o < NPTS) nbr[(g / NPTS) * NROW + o] = ii[g];
}

// ---- repack w_blocks (f32, 4 layers x 27 x 64 x 64) into bf16 MFMA B-fragment order ----
__global__ __launch_bounds__(256) void k_repack(const float* __restrict__ w,
                                                unsigned short* __restrict__ wp) {
  int g = blockIdx.x * 256 + threadIdx.x;          // 108*4096 total
  int e = g & 7, l = (g >> 3) & 63, f = (g >> 9) & 7, rest = g >> 12; // rest = L*27+k
  int t = f >> 1, h = f & 1;
  int kk = h * 32 + (l >> 4) * 8 + e;
  int cc = t * 16 + (l & 15);
  wp[g] = f2bf(w[(rest * 64 + kk) * 64 + cc]);
}

// ---- stats pass 1 (f32 input, first IN only) ----
__global__ __launch_bounds__(256) void k_stats1_f32(const float* __restrict__ F,
                                                    float* __restrict__ P) {
  int lane = threadIdx.x & 63, wave = threadIdx.x >> 6;
  int batch = blockIdx.x >> 7, bb = blockIdx.x & 127;
  const float* Fb = F + (size_t)batch * NB * 64;
  float s = 0.f, ss = 0.f;
  for (int r = bb * 4 + wave; r < NB; r += 512) {
    float v = Fb[(size_t)r * 64 + lane];
    s += v; ss += v * v;
  }
  __shared__ float ls[4][64], lss[4][64];
  ls[wave][lane] = s; lss[wave][lane] = ss;
  __syncthreads();
  if (threadIdx.x < 64) {
    float S  = ls[0][lane] + ls[1][lane] + ls[2][lane] + ls[3][lane];
    float SS = lss[0][lane] + lss[1][lane] + lss[2][lane] + lss[3][lane];
    P[blockIdx.x * 128 + lane]      = S;
    P[blockIdx.x * 128 + 64 + lane] = SS;
  }
}

// ---- stats pass 1 (bf16 input), short8 vectorized ----
__global__ __launch_bounds__(256) void k_stats1_bf(const unsigned short* __restrict__ F,
                                                   float* __restrict__ P) {
  int t = threadIdx.x;
  int cg = t & 7;        // channel group (8 channels)
  int rg = t >> 3;       // 0..31
  int batch = blockIdx.x >> 7, bb = blockIdx.x & 127;
  const unsigned short* Fb = F + (size_t)batch * NB * 64;
  float s[8], ss[8];
#pragma unroll
  for (int e = 0; e < 8; ++e) { s[e] = 0.f; ss[e] = 0.f; }
  for (int r = bb * 32 + rg; r < NB; r += 128 * 32) {
    short8 v = *(const short8*)(Fb + (size_t)r * 64 + cg * 8);
#pragma unroll
    for (int e = 0; e < 8; ++e) {
      float f = bf2f((unsigned short)v[e]);
      s[e] += f; ss[e] += f * f;
    }
  }
  __shared__ float sm[2][32][64];
#pragma unroll
  for (int e = 0; e < 8; ++e) {
    sm[0][rg][cg * 8 + e] = s[e];
    sm[1][rg][cg * 8 + e] = ss[e];
  }
  __syncthreads();
  if (t < 64) {
    float S = 0.f, SS = 0.f;
#pragma unroll 8
    for (int g = 0; g < 32; ++g) { S += sm[0][g][t]; SS += sm[1][g][t]; }
    P[blockIdx.x * 128 + t]      = S;
    P[blockIdx.x * 128 + 64 + t] = SS;
  }
}

// ---- stats pass 2 ----
__global__ void k_stats2(const float* __restrict__ P, float* __restrict__ MRS) {
  int t = threadIdx.x;
  if (t >= 128) return;
  int b = t >> 6, c = t & 63;
  float S = 0.f, SS = 0.f;
  for (int blk = 0; blk < 128; ++blk) {
    S  += P[(b * 128 + blk) * 128 + c];
    SS += P[(b * 128 + blk) * 128 + 64 + c];
  }
  float mean = S * (1.f / NB);
  float var  = SS * (1.f / NB) - mean * mean;
  MRS[b * 128 + c]      = mean;
  MRS[b * 128 + 64 + c] = rsqrtf(var + 1e-5f);
}

// ---- first apply: f32 feats -> bf16 X, relu(norm) ----
__global__ __launch_bounds__(256) void k_apply_f2b(const float* __restrict__ F,
                                                   const float* __restrict__ MRS,
                                                   unsigned short* __restrict__ O) {
  int i = blockIdx.x * 256 + threadIdx.x;          // 960000 groups of 8
  int r = i >> 3, cb = (i & 7) * 8;
  int b = (r >= NB) ? 1 : 0;
  f32x4 v0 = *((const f32x4*)F + i * 2);
  f32x4 v1 = *((const f32x4*)F + i * 2 + 1);
  short8 o;
#pragma unroll
  for (int e = 0; e < 4; ++e) {
    float f = (v0[e] - MRS[b * 128 + cb + e]) * MRS[b * 128 + 64 + cb + e];
    o[e] = (short)f2bf(fmaxf(f, 0.f));
    float g = (v1[e] - MRS[b * 128 + cb + 4 + e]) * MRS[b * 128 + 64 + cb + 4 + e];
    o[e + 4] = (short)f2bf(fmaxf(g, 0.f));
  }
  *((short8*)O + i) = o;
}

// ---- O = relu(norm(F)), bf16 -> bf16 (in-place safe) ----
__global__ __launch_bounds__(256) void k_apply_bf(const unsigned short* __restrict__ F,
                                                  const float* __restrict__ MRS,
                                                  unsigned short* __restrict__ O) {
  int i = blockIdx.x * 256 + threadIdx.x;
  int r = i >> 3, cb = (i & 7) * 8;
  int b = (r >= NB) ? 1 : 0;
  short8 v = *((const short8*)F + i);
  short8 o;
#pragma unroll
  for (int e = 0; e < 8; ++e) {
    float f = bf2f((unsigned short)v[e]);
    f = (f - MRS[b * 128 + cb + e]) * MRS[b * 128 + 64 + cb + e];
    o[e] = (short)f2bf(fmaxf(f, 0.f));
  }
  *((short8*)O + i) = o;
}

// ---- X = relu(norm(H2) + X), bf16 ----
__global__ __launch_bounds__(256) void k_apply_res_bf(const unsigned short* __restrict__ H2,
                                                      const float* __restrict__ MRS,
                                                      unsigned short* __restrict__ X) {
  int i = blockIdx.x * 256 + threadIdx.x;
  int r = i >> 3, cb = (i & 7) * 8;
  int b = (r >= NB) ? 1 : 0;
  short8 v = *((const short8*)H2 + i);
  short8 xv = *((const short8*)X + i);
  short8 o;
#pragma unroll
  for (int e = 0; e < 8; ++e) {
    float f = bf2f((unsigned short)v[e]);
    f = (f - MRS[b * 128 + cb + e]) * MRS[b * 128 + 64 + cb + e];
    f += bf2f((unsigned short)xv[e]);
    o[e] = (short)f2bf(fmaxf(f, 0.f));
  }
  *((short8*)X + i) = o;
}

// ---- gather-MFMA sparse conv, 64->64, bf16 in/out, 64 rows per wave ----
__global__ __launch_bounds__(256) void k_conv64(const unsigned short* __restrict__ X,
                                                const unsigned short* __restrict__ WP,
                                                const int* __restrict__ nbr,
                                                unsigned short* __restrict__ Y) {
  const int lane = threadIdx.x & 63, wave = threadIdx.x >> 6;
  const int j0 = blockIdx.x * 256 + wave * 64;
  const int lrow = lane & 15, lk = lane >> 4;
  f32x4 acc[4][4];   // [rowgroup][coltile]
#pragma unroll
  for (int g = 0; g < 4; ++g)
#pragma unroll
    for (int c = 0; c < 4; ++c) acc[g][c] = (f32x4){0.f, 0.f, 0.f, 0.f};

  for (int k = 0; k < TAPS; ++k) {
    const int* np = nbr + (size_t)k * NROW + j0 + lrow;
    int idx[4];
    idx[0] = np[0]; idx[1] = np[16]; idx[2] = np[32]; idx[3] = np[48];
    short8 a[4][2];
#pragma unroll
    for (int g = 0; g < 4; ++g) {
      a[g][0] = (short8){0,0,0,0,0,0,0,0};
      a[g][1] = (short8){0,0,0,0,0,0,0,0};
      if (idx[g] >= 0) {
        const unsigned short* rp = X + (size_t)idx[g] * 64 + lk * 8;
        a[g][0] = *(const short8*)rp;
        a[g][1] = *(const short8*)(rp + 32);
      }
    }
    const unsigned short* wpk = WP + k * 4096 + lane * 8;
#pragma unroll
    for (int ct = 0; ct < 4; ++ct) {
      short8 b0 = *(const short8*)(wpk + ct * 1024);
      short8 b1 = *(const short8*)(wpk + ct * 1024 + 512);
#pragma unroll
      for (int g = 0; g < 4; ++g) {
        acc[g][ct] = __builtin_amdgcn_mfma_f32_16x16x32_bf16(a[g][0], b0, acc[g][ct], 0, 0, 0);
        acc[g][ct] = __builtin_amdgcn_mfma_f32_16x16x32_bf16(a[g][1], b1, acc[g][ct], 0, 0, 0);
      }
    }
  }
  // C/D: col = lane&15, row = (lane>>4)*4 + reg
#pragma unroll
  for (int g = 0; g < 4; ++g) {
    unsigned short* yp = Y + (size_t)(j0 + g * 16 + lk * 4) * 64 + lrow;
#pragma unroll
    for (int r = 0; r < 4; ++r) {
      yp[r * 64 +  0] = f2bf(acc[g][0][r]);
      yp[r * 64 + 16] = f2bf(acc[g][1][r]);
      yp[r * 64 + 32] = f2bf(acc[g][2][r]);
      yp[r * 64 + 48] = f2bf(acc[g][3][r]);
    }
  }
}

// ---- final stage 1: D[k][i] = X[i] . WF[k]  (MFMA GEMM 120064x64 @ 64x27) ----
__global__ __launch_bounds__(256) void k_dfin(const unsigned short* __restrict__ X,
                                              const float* __restrict__ WF,
                                              float* __restrict__ D) {
  const int lane = threadIdx.x & 63, wave = threadIdx.x >> 6;
  const int j0 = blockIdx.x * 64 + wave * 16;
  const int lrow = lane & 15, lk = lane >> 4;
  const unsigned short* rp = X + (size_t)(j0 + lrow) * 64 + lk * 8;
  short8 a0 = *(const short8*)rp;
  short8 a1 = *(const short8*)(rp + 32);
  short8 b[2][2];
#pragma unroll
  for (int ct = 0; ct < 2; ++ct) {
    int col = ct * 16 + lrow;
#pragma unroll
    for (int h = 0; h < 2; ++h) {
#pragma unroll
      for (int e = 0; e < 8; ++e)
        b[ct][h][e] = (col < TAPS) ? (short)f2bf(WF[col * 64 + h * 32 + lk * 8 + e]) : (short)0;
    }
  }
  f32x4 acc0 = {0,0,0,0}, acc1 = {0,0,0,0};
  acc0 = __builtin_amdgcn_mfma_f32_16x16x32_bf16(a0, b[0][0], acc0, 0, 0, 0);
  acc0 = __builtin_amdgcn_mfma_f32_16x16x32_bf16(a1, b[0][1], acc0, 0, 0, 0);
  acc1 = __builtin_amdgcn_mfma_f32_16x16x32_bf16(a0, b[1][0], acc1, 0, 0, 0);
  acc1 = __builtin_amdgcn_mfma_f32_16x16x32_bf16(a1, b[1][1], acc1, 0, 0, 0);
  float* dp0 = D + (size_t)lrow * NROW + j0 + lk * 4;
  float* dp1 = D + (size_t)(16 + lrow) * NROW + j0 + lk * 4;
#pragma unroll
  for (int r = 0; r < 4; ++r) { dp0[r] = acc0[r]; dp1[r] = acc1[r]; }
}

// ---- final stage 2: out[j] = bias + sum_k D[k][nbr[k][j]] ----
__global__ __launch_bounds__(256) void k_gfin(const float* __restrict__ D,
                                              const int* __restrict__ nbr,
                                              const float* __restrict__ BF,
                                              float* __restrict__ out) {
  int j = blockIdx.x * 256 + threadIdx.x;
  if (j >= NPTS) return;
  float acc = BF[0];
#pragma unroll
  for (int k = 0; k < TAPS; ++k) {
    int idx = nbr[(size_t)k * NROW + j];
    if (idx >= 0) acc += D[(size_t)k * NROW + idx];
  }
  out[j] = acc;
}

extern "C" void kernel_launch(void* const* d_in, const int* in_sizes, int n_in,
                              void* d_out, int out_size, void* d_ws, size_t ws_size,
                              hipStream_t stream) {
  (void)in_sizes; (void)n_in; (void)out_size; (void)ws_size;
  const float* feats = (const float*)d_in[0];
  const float* wblk  = (const float*)d_in[1];
  const float* wfin  = (const float*)d_in[2];
  const float* bfin  = (const float*)d_in[3];
  const int* in_idx  = (const int*)d_in[4];
  const int* out_idx = (const int*)d_in[5];

  char* p = (char*)d_ws;
  size_t off = 0;
  auto carve = [&](size_t bytes) {
    void* r = p + off; off += (bytes + 255) & ~(size_t)255; return r;
  };
  int*            nbr = (int*)carve((size_t)TAPS * NROW * 4);             // 12.97 MB
  unsigned short* Xb  = (unsigned short*)carve((size_t)NROW * 64 * 2);    // 15.37 MB
  unsigned short* Hb  = (unsigned short*)carve((size_t)NROW * 64 * 2);
  unsigned short* H2b = (unsigned short*)carve((size_t)NROW * 64 * 2);
  unsigned short* WP  = (unsigned short*)carve(108u * 4096u * 2);         // 0.88 MB
  float*          D   = (float*)carve((size_t)TAPS * NROW * 4);           // 12.97 MB
  float*          P   = (float*)carve(256 * 128 * 4);
  float*          MRS = (float*)carve(256 * 4);

  hipMemsetAsync(nbr, 0xFF, (size_t)TAPS * NROW * 4, stream);
  k_build_nbr<<<(TAPS * NPTS + 255) / 256, 256, 0, stream>>>(out_idx, in_idx, nbr);
  k_repack<<<1728, 256, 0, stream>>>(wblk, WP);

  // x = relu(IN(feats))
  k_stats1_f32<<<256, 256, 0, stream>>>(feats, P);
  k_stats2<<<1, 128, 0, stream>>>(P, MRS);
  k_apply_f2b<<<3750, 256, 0, stream>>>(feats, MRS, Xb);

  // block 0
  k_conv64<<<NROW / 256, 256, 0, stream>>>(Xb, WP + 0 * 110592, nbr, Hb);
  k_stats1_bf<<<256, 256, 0, stream>>>(Hb, P);
  k_stats2<<<1, 128, 0, stream>>>(P, MRS);
  k_apply_bf<<<3750, 256, 0, stream>>>(Hb, MRS, Hb);
  k_conv64<<<NROW / 256, 256, 0, stream>>>(Hb, WP + 1 * 110592, nbr, H2b);
  k_stats1_bf<<<256, 256, 0, stream>>>(H2b, P);
  k_stats2<<<1, 128, 0, stream>>>(P, MRS);
  k_apply_res_bf<<<3750, 256, 0, stream>>>(H2b, MRS, Xb);

  // block 1
  k_conv64<<<NROW / 256, 256, 0, stream>>>(Xb, WP + 2 * 110592, nbr, Hb);
  k_stats1_bf<<<256, 256, 0, stream>>>(Hb, P);
  k_stats2<<<1, 128, 0, stream>>>(P, MRS);
  k_apply_bf<<<3750, 256, 0, stream>>>(Hb, MRS, Hb);
  k_conv64<<<NROW / 256, 256, 0, stream>>>(Hb, WP + 3 * 110592, nbr, H2b);
  k_stats1_bf<<<256, 256, 0, stream>>>(H2b, P);
  k_stats2<<<1, 128, 0, stream>>>(P, MRS);
  k_apply_res_bf<<<3750, 256, 0, stream>>>(H2b, MRS, Xb);

  // final 64->1 conv + bias: D = X.WF^T then gather-sum
  k_dfin<<<NROW / 64, 256, 0, stream>>>(Xb, wfin, D);
  k_gfin<<<NROW / 256, 256, 0, stream>>>(D, nbr, bfin, (float*)d_out);
}